// Round 7
// baseline (178.218 us; speedup 1.0000x reference)
//
#include <hip/hip_runtime.h>
#include <math.h>

// Problem constants (x: (5,1,256,64,64) f32)
constexpr int NIMG = 5;
constexpr int CCH  = 256;   // channels (both c and d)
constexpr int HWP  = 4096;  // H*W
constexpr int PT   = CCH * HWP;  // elems per image = 1048576

// Tiling: 16 d x 256 p per block; wave wv owns d-rows d0w..d0w+3 (wave-uniform
// -> w operand via s_load/SGPR, off the LDS pipe). Lanes own 4 p each.
// K-step 8, double-buffered LDS for x only (2 x 40 KB).
constexpr int BK = 8;
constexpr int NSTEP = CCH / BK;   // 32

// Async global->LDS, 16B/lane. LDS dest is wave-uniform base; HW adds lane*16.
__device__ __forceinline__ void gload16(const float* g, float* l) {
    __builtin_amdgcn_global_load_lds(
        (const __attribute__((address_space(1))) unsigned int*)g,
        (__attribute__((address_space(3))) unsigned int*)l, 16, 0, 0);
}

// -----------------------------------------------------------------------------
// Fully fused, scalar-w GEMM + edge epilogue.
//   acc_s[n] = sum_c x[n,c,p]*(W1+W2)[c,d]   (wsa = w1+w2 per cc: identical
//   acc_2[n] = sum_c x[n,c,p]*W2[c,d]         fp32 chain as passing versions)
//   u = x - acc_s - b ; v = acc_2 ; e=|u[j]-v[i]| ; thresholded weighted sum.
// w reads are wave-uniform (d0w from blockIdx+waveid) -> SGPR loads, so the
// LDS pipe only carries x (5 ds_read_b128/cc vs 336 VALU-cyc) -> VALU-bound.
// -----------------------------------------------------------------------------
__global__ __launch_bounds__(256, 2) void fused_all(
    const float* __restrict__ x, const float* __restrict__ w,
    const float* __restrict__ bias, float* __restrict__ out)
{
    const int lane = threadIdx.x & 63;
    const int wv   = __builtin_amdgcn_readfirstlane(threadIdx.x >> 6);
    const int d0w  = blockIdx.x * 16 + wv * 4;   // wave's 4 d-rows (uniform)
    const int p0   = blockIdx.y * 256;           // block's p-slice
    const int pl   = p0 + lane * 4;              // lane's 4 p-cols

    __shared__ float xs[2][NIMG][BK][256];       // 2 x 40 KB

    float acc_s[NIMG][4][4] = {};  // sum_c x*(W1+W2)
    float acc_2[NIMG][4][4] = {};  // sum_c x*W2

    // Stage one K-step into buffer b: 40 rows (n,cc) of 1 KB; wave wv stages
    // rows rho = wv + 4k (k=0..9). Uniform LDS dest per gload16.
    auto stage = [&](int b, int c0) {
        #pragma unroll
        for (int k = 0; k < 10; ++k) {
            const int rho = wv + 4 * k;
            const int n = rho >> 3, cc = rho & 7;
            gload16(&x[(size_t)n * PT + (size_t)(c0 + cc) * HWP + p0 + lane * 4],
                    &xs[b][n][cc][0]);
        }
    };

    stage(0, 0);

    for (int st = 0; st < NSTEP; ++st) {
        const int cur = st & 1;
        if (st + 1 < NSTEP) {
            stage(cur ^ 1, (st + 1) * BK);
            asm volatile("s_waitcnt vmcnt(10)" ::: "memory");  // step st staged
        } else {
            asm volatile("s_waitcnt vmcnt(0)" ::: "memory");
        }
        __builtin_amdgcn_s_barrier();   // buffer cur ready (all waves)

        #pragma unroll
        for (int cc = 0; cc < BK; ++cc) {
            const int c = st * BK + cc;
            // wave-uniform w loads -> SGPRs (s_load_dwordx4)
            const float4 w1v = *reinterpret_cast<const float4*>(
                &w[(size_t)c * CCH + d0w]);
            const float4 w2v = *reinterpret_cast<const float4*>(
                &w[(size_t)(CCH + c) * CCH + d0w]);
            const float w2a[4] = {w2v.x, w2v.y, w2v.z, w2v.w};
            const float wsa[4] = {w1v.x + w2v.x, w1v.y + w2v.y,
                                  w1v.z + w2v.z, w1v.w + w2v.w};
            #pragma unroll
            for (int n = 0; n < NIMG; ++n) {
                const float4 xv = *reinterpret_cast<const float4*>(
                    &xs[cur][n][cc][lane * 4]);
                const float xa[4] = {xv.x, xv.y, xv.z, xv.w};
                #pragma unroll
                for (int r = 0; r < 4; ++r) {
                    #pragma unroll
                    for (int q = 0; q < 4; ++q) {
                        acc_s[n][r][q] = fmaf(wsa[r], xa[q], acc_s[n][r][q]);
                        acc_2[n][r][q] = fmaf(w2a[r], xa[q], acc_2[n][r][q]);
                    }
                }
            }
        }
        __builtin_amdgcn_s_barrier();   // compute done before re-staging cur^1
    }

    // ---------------- fused epilogue: edges + threshold + reduce ----------------
    #pragma unroll
    for (int r = 0; r < 4; ++r) {
        const int d = d0w + r;
        const float bd = bias[d];
        const size_t base = (size_t)d * HWP + pl;

        float xa[NIMG][4], ua[NIMG][4], va[NIMG][4];
        #pragma unroll
        for (int n = 0; n < NIMG; ++n) {
            const float4 xv = *reinterpret_cast<const float4*>(&x[(size_t)n * PT + base]);
            const float xt[4] = {xv.x, xv.y, xv.z, xv.w};
            #pragma unroll
            for (int q = 0; q < 4; ++q) {
                xa[n][q] = xt[q];
                ua[n][q] = xt[q] - acc_s[n][r][q] - bd;
                va[n][q] = acc_2[n][r][q];
            }
        }

        #pragma unroll
        for (int i = 0; i < NIMG; ++i) {
            float ho[4];
            #pragma unroll
            for (int q = 0; q < 4; ++q) {
                float e[NIMG];
                float sumsq = 0.0f;
                #pragma unroll
                for (int j = 0; j < NIMG; ++j) {
                    e[j] = fabsf(ua[j][q] - va[i][q]);
                    sumsq = fmaf(e[j], e[j], sumsq);
                }
                const float m = fmaxf(sqrtf(sumsq), 1e-12f);
                float h = 0.0f;
                #pragma unroll
                for (int j = 0; j < NIMG; ++j) {
                    const float en = e[j] / m;
                    if (en > 0.35f) h = fmaf(e[j], xa[j][q], h);
                }
                ho[q] = h;
            }
            const float4 ov = {ho[0], ho[1], ho[2], ho[3]};
            *reinterpret_cast<float4*>(&out[(size_t)i * PT + base]) = ov;
        }
    }
}

extern "C" void kernel_launch(void* const* d_in, const int* in_sizes, int n_in,
                              void* d_out, int out_size, void* d_ws, size_t ws_size,
                              hipStream_t stream) {
    const float* x    = (const float*)d_in[0];
    const float* w    = (const float*)d_in[1];
    const float* bias = (const float*)d_in[2];
    float* out = (float*)d_out;

    dim3 g(CCH / 16, HWP / 256);   // 16 d-blocks x 16 p-blocks = 256 blocks
    fused_all<<<g, 256, 0, stream>>>(x, w, bias, out);
}

// Round 8
// 92.094 us; speedup vs baseline: 1.9352x; 1.9352x over previous
//
#include <hip/hip_runtime.h>
#include <math.h>

// Problem constants (x: (5,1,256,64,64) f32)
constexpr int NIMG = 5;
constexpr int CCH  = 256;   // channels (both c and d)
constexpr int HWP  = 4096;  // H*W
constexpr int PT   = CCH * HWP;  // elems per image = 1048576

// Tiling: 64 d x 64 p per block, 256 threads, micro-tile 4d x 4p x 5 images.
// BK=32 double-buffered: LDS = 2*(5*32*64 + 2*32*64)*4B = 112 KB, 1 block/CU.
// Grid 256 blocks = exactly one per CU. Per wave-cc: 7 ds_read_b128 (84 cyc
// CU-LDS-pipe) vs 164 VALU instr (328 SIMD-cyc over 4 SIMDs = 82/wave):
// both pipes balanced -> ~36 us floor.
constexpr int BD = 64;
constexpr int BP = 64;
constexpr int BK = 32;
constexpr int NSTEP = CCH / BK;   // 8

// Async global->LDS, 16B/lane. LDS dest is wave-uniform base; HW adds lane*16.
__device__ __forceinline__ void gload16(const float* g, float* l) {
    __builtin_amdgcn_global_load_lds(
        (const __attribute__((address_space(1))) unsigned int*)g,
        (__attribute__((address_space(3))) unsigned int*)l, 16, 0, 0);
}

// -----------------------------------------------------------------------------
// Fully fused kernel.
//   acc_s[n] = sum_c x[n,c,p]*(W1+W2)[c,d]   (wsa = w1+w2 per cc: identical
//   acc_2[n] = sum_c x[n,c,p]*W2[c,d]         fp32 chain as passing versions)
//   u = x[n,d,p] - acc_s - b ; v = acc_2 ; e=|u[j]-v[i]| ; row-norm threshold;
//   out[i] = sum_j kept_e * x[j].   Epilogue math verbatim -> bit-identical.
// -----------------------------------------------------------------------------
__global__ __launch_bounds__(256, 1) void fused_all(
    const float* __restrict__ x, const float* __restrict__ w,
    const float* __restrict__ bias, float* __restrict__ out)
{
    const int t  = threadIdx.x;
    const int tp = t & 15;   // p-frag: cols p0 + tp*4 .. +3
    const int td = t >> 4;   // d-frag: rows d0 + td*4 .. +3
    const int p0 = blockIdx.x * BP;
    const int d0 = blockIdx.y * BD;

    __shared__ float xs[2][NIMG][BK][BP];   // 80 KB
    __shared__ float ws[2][2][BK][BD];      // 32 KB  ([mat]: 0=w1, 1=w2)

    float acc_s[NIMG][4][4] = {};  // sum_c x*(W1+W2)
    float acc_2[NIMG][4][4] = {};  // sum_c x*W2

    const int wv = t >> 6, l = t & 63;
    const int sr = l >> 4;          // row within 4-row (1KB) chunk
    const int scol = (l & 15) * 4;  // col within 64-float row

    // Stage one K-step into buffer b: 40 x-chunks + 16 w-chunks of 1KB each;
    // wave wv stages 10 x + 4 w = 14 gload16 (uniform LDS dest per call).
    auto stage = [&](int b, int c0) {
        #pragma unroll
        for (int k = 0; k < 10; ++k) {
            const int ch  = wv + 4 * k;        // 0..39
            const int n   = ch >> 3;
            const int ccb = (ch & 7) * 4;
            gload16(&x[(size_t)n * PT + (size_t)(c0 + ccb + sr) * HWP + p0 + scol],
                    &xs[b][n][ccb][0]);
        }
        #pragma unroll
        for (int m = 0; m < 4; ++m) {
            const int wc  = wv + 4 * m;        // 0..15
            const int mat = wc >> 3;           // 0: w1, 1: w2
            const int kb  = (wc & 7) * 4;
            gload16(&w[(size_t)(mat * CCH + c0 + kb + sr) * CCH + d0 + scol],
                    &ws[b][mat][kb][0]);
        }
    };

    stage(0, 0);

    for (int st = 0; st < NSTEP; ++st) {
        const int cur = st & 1;
        if (st + 1 < NSTEP) {
            stage(cur ^ 1, (st + 1) * BK);
            asm volatile("s_waitcnt vmcnt(14)" ::: "memory");  // step st staged
        } else {
            asm volatile("s_waitcnt vmcnt(0)" ::: "memory");
        }
        __builtin_amdgcn_s_barrier();   // buffer cur ready (all waves)

        #pragma unroll 8
        for (int cc = 0; cc < BK; ++cc) {
            const float4 w1v = *reinterpret_cast<const float4*>(&ws[cur][0][cc][td * 4]);
            const float4 w2v = *reinterpret_cast<const float4*>(&ws[cur][1][cc][td * 4]);
            const float w2a[4] = {w2v.x, w2v.y, w2v.z, w2v.w};
            const float wsa[4] = {w1v.x + w2v.x, w1v.y + w2v.y,
                                  w1v.z + w2v.z, w1v.w + w2v.w};
            #pragma unroll
            for (int n = 0; n < NIMG; ++n) {
                const float4 xv = *reinterpret_cast<const float4*>(&xs[cur][n][cc][tp * 4]);
                const float xa[4] = {xv.x, xv.y, xv.z, xv.w};
                #pragma unroll
                for (int r = 0; r < 4; ++r) {
                    #pragma unroll
                    for (int q = 0; q < 4; ++q) {
                        acc_s[n][r][q] = fmaf(wsa[r], xa[q], acc_s[n][r][q]);
                        acc_2[n][r][q] = fmaf(w2a[r], xa[q], acc_2[n][r][q]);
                    }
                }
            }
        }
        __builtin_amdgcn_s_barrier();   // compute done before re-staging cur^1
    }

    // ---------------- fused epilogue: edges + threshold + reduce ----------------
    #pragma unroll
    for (int r = 0; r < 4; ++r) {
        const int d = d0 + td * 4 + r;
        const float bd = bias[d];
        const size_t base = (size_t)d * HWP + p0 + tp * 4;

        float xa[NIMG][4], ua[NIMG][4], va[NIMG][4];
        #pragma unroll
        for (int n = 0; n < NIMG; ++n) {
            const float4 xv = *reinterpret_cast<const float4*>(&x[(size_t)n * PT + base]);
            const float xt[4] = {xv.x, xv.y, xv.z, xv.w};
            #pragma unroll
            for (int q = 0; q < 4; ++q) {
                xa[n][q] = xt[q];
                ua[n][q] = xt[q] - acc_s[n][r][q] - bd;
                va[n][q] = acc_2[n][r][q];
            }
        }

        #pragma unroll
        for (int i = 0; i < NIMG; ++i) {
            float ho[4];
            #pragma unroll
            for (int q = 0; q < 4; ++q) {
                float e[NIMG];
                float sumsq = 0.0f;
                #pragma unroll
                for (int j = 0; j < NIMG; ++j) {
                    e[j] = fabsf(ua[j][q] - va[i][q]);
                    sumsq = fmaf(e[j], e[j], sumsq);
                }
                const float m = fmaxf(sqrtf(sumsq), 1e-12f);
                float h = 0.0f;
                #pragma unroll
                for (int j = 0; j < NIMG; ++j) {
                    const float en = e[j] / m;
                    if (en > 0.35f) h = fmaf(e[j], xa[j][q], h);
                }
                ho[q] = h;
            }
            const float4 ov = {ho[0], ho[1], ho[2], ho[3]};
            *reinterpret_cast<float4*>(&out[(size_t)i * PT + base]) = ov;
        }
    }
}

extern "C" void kernel_launch(void* const* d_in, const int* in_sizes, int n_in,
                              void* d_out, int out_size, void* d_ws, size_t ws_size,
                              hipStream_t stream) {
    const float* x    = (const float*)d_in[0];
    const float* w    = (const float*)d_in[1];
    const float* bias = (const float*)d_in[2];
    float* out = (float*)d_out;

    dim3 g(HWP / BP, CCH / BD);   // 64 x 4 = 256 blocks = 1 per CU
    fused_all<<<g, 256, 0, stream>>>(x, w, bias, out);
}